// Round 1
// baseline (250.543 us; speedup 1.0000x reference)
//
#include <hip/hip_runtime.h>

#define BS   8
#define NCH  7
#define PX   409600      // 640*640
#define NBIN 65536
#define WIN_LO 0x3000u   // LDS histogram window over top-16 bits: [0x3000, 0x4000)
#define WIN_SZ 4096
#define EPSF 1e-6f

__device__ __forceinline__ float sigf(float x) {
    return 1.0f / (1.0f + __expf(-x));
}

__device__ __forceinline__ unsigned wred_u(unsigned v) {
    #pragma unroll
    for (int o = 32; o; o >>= 1) v += __shfl_down(v, o);
    return v;
}

__device__ __forceinline__ float wred_f(float v) {
    #pragma unroll
    for (int o = 32; o; o >>= 1) v += __shfl_down(v, o);
    return v;
}

// ---------------- K1: per-sample top-16-bit histogram of negatives + n_pos ----------
__global__ __launch_bounds__(256) void k_hist(const float* __restrict__ preds,
                                              const int* __restrict__ mask,
                                              unsigned* __restrict__ hist1,
                                              unsigned* __restrict__ n_pos) {
    int b = blockIdx.y;
    const float* pr = preds + ((size_t)b * NCH + 6) * PX;
    const int* mk = mask + (size_t)b * PX;
    __shared__ unsigned lh[WIN_SZ];
    for (int j = threadIdx.x; j < WIN_SZ; j += blockDim.x) lh[j] = 0u;
    __syncthreads();
    unsigned pos_cnt = 0, zero_cnt = 0;
    for (int i = blockIdx.x * blockDim.x + threadIdx.x; i < PX; i += gridDim.x * blockDim.x) {
        float pn = sigf(pr[i]) * (float)mk[i];
        if (pn >= 0.5f) {
            pos_cnt++;
        } else {
            unsigned bits = __float_as_uint(pn);
            if (bits == 0u) {
                zero_cnt++;                       // huge bin (mask==0) -> block-reduced
            } else {
                unsigned hb = bits >> 16;
                if (hb >= WIN_LO && hb < WIN_LO + WIN_SZ)
                    atomicAdd(&lh[hb - WIN_LO], 1u);
                else
                    atomicAdd(&hist1[(size_t)b * NBIN + hb], 1u);  // rare fallback
            }
        }
    }
    __syncthreads();
    for (int j = threadIdx.x; j < WIN_SZ; j += blockDim.x) {
        unsigned c = lh[j];
        if (c) atomicAdd(&hist1[(size_t)b * NBIN + WIN_LO + j], c);
    }
    __shared__ unsigned ws2[2][4];
    unsigned pv = wred_u(pos_cnt), zv = wred_u(zero_cnt);
    int lane = threadIdx.x & 63, wid = threadIdx.x >> 6;
    if (lane == 0) { ws2[0][wid] = pv; ws2[1][wid] = zv; }
    __syncthreads();
    if (threadIdx.x == 0) {
        unsigned pt = 0, zt = 0;
        #pragma unroll
        for (int w = 0; w < 4; w++) { pt += ws2[0][w]; zt += ws2[1][w]; }
        if (pt) atomicAdd(&n_pos[b], pt);
        if (zt) atomicAdd(&hist1[(size_t)b * NBIN], zt);
    }
}

// ------------- device helper: 256-thread suffix-scan select over 65536 bins ---------
// Finds bin such that (count of elements in bins >= bin) >= k and strictly < k above it.
// out_rank = remaining 1-based rank within that bin (from the top).
__device__ void select_bin(const unsigned* __restrict__ h, unsigned k,
                           unsigned* out_bin, unsigned* out_rank) {
    __shared__ unsigned cs[256];
    __shared__ unsigned sel_chunk, sel_rem;
    int t = threadIdx.x;
    unsigned s = 0;
    const unsigned* hp = h + t * 256;
    #pragma unroll 8
    for (int j = 0; j < 256; j++) s += hp[j];
    cs[t] = s;
    __syncthreads();
    #pragma unroll
    for (int off = 1; off < 256; off <<= 1) {
        unsigned v = cs[t];
        unsigned a = (t + off < 256) ? cs[t + off] : 0u;
        __syncthreads();
        cs[t] = v + a;
        __syncthreads();
    }
    {
        unsigned sfx  = cs[t];
        unsigned sfx1 = (t < 255) ? cs[t + 1] : 0u;
        if (sfx >= k && sfx1 < k) { sel_chunk = (unsigned)t; sel_rem = k - sfx1; }
    }
    __syncthreads();
    unsigned chunk = sel_chunk, krem = sel_rem;
    cs[t] = h[chunk * 256 + t];
    __syncthreads();
    #pragma unroll
    for (int off = 1; off < 256; off <<= 1) {
        unsigned v = cs[t];
        unsigned a = (t + off < 256) ? cs[t + off] : 0u;
        __syncthreads();
        cs[t] = v + a;
        __syncthreads();
    }
    {
        unsigned sfx  = cs[t];
        unsigned sfx1 = (t < 255) ? cs[t + 1] : 0u;
        if (sfx >= krem && sfx1 < krem) {
            *out_bin  = chunk * 256 + (unsigned)t;
            *out_rank = krem - sfx1;
        }
    }
    __syncthreads();
}

// ---------------- K2: find top-16-bit bin of the k-th largest negative --------------
__global__ __launch_bounds__(256) void k_find_hi(const unsigned* __restrict__ hist1,
                                                 const unsigned* __restrict__ n_pos,
                                                 unsigned* __restrict__ hi_bin,
                                                 unsigned* __restrict__ rankv,
                                                 unsigned* __restrict__ activev,
                                                 float* __restrict__ thr) {
    int b = blockIdx.x;
    unsigned np_ = n_pos[b];
    unsigned k = np_ * 3u;
    unsigned nneg = (unsigned)PX - np_;
    if (!(nneg > k && k > 0u)) {
        if (threadIdx.x == 0) { activev[b] = 0u; thr[b] = -1.0f; }  // M = 1 everywhere
        return;
    }
    __shared__ unsigned rb, rr;
    select_bin(hist1 + (size_t)b * NBIN, k, &rb, &rr);
    if (threadIdx.x == 0) {
        activev[b] = 1u;
        hi_bin[b] = rb;
        rankv[b] = rr;
        if (rb == 0u) thr[b] = 0.0f;   // zero bin: all elements are exactly 0.0f
    }
}

// ---------------- K3: refine — low-16-bit histogram within selected hi bin ----------
__global__ __launch_bounds__(256) void k_refine(const float* __restrict__ preds,
                                                const int* __restrict__ mask,
                                                const unsigned* __restrict__ hi_bin,
                                                const unsigned* __restrict__ activev,
                                                unsigned* __restrict__ hist2) {
    int b = blockIdx.y;
    if (!activev[b]) return;
    unsigned hi = hi_bin[b];
    if (hi == 0u) return;   // thr already resolved to 0.0f
    const float* pr = preds + ((size_t)b * NCH + 6) * PX;
    const int* mk = mask + (size_t)b * PX;
    unsigned* h2 = hist2 + (size_t)b * NBIN;
    for (int i = blockIdx.x * blockDim.x + threadIdx.x; i < PX; i += gridDim.x * blockDim.x) {
        float pn = sigf(pr[i]) * (float)mk[i];
        if (pn < 0.5f) {
            unsigned bits = __float_as_uint(pn);
            if ((bits >> 16) == hi) atomicAdd(&h2[bits & 0xFFFFu], 1u);
        }
    }
}

// ---------------- K4: resolve exact threshold bits ----------------------------------
__global__ __launch_bounds__(256) void k_find_lo(const unsigned* __restrict__ hist2,
                                                 const unsigned* __restrict__ hi_bin,
                                                 const unsigned* __restrict__ rankv,
                                                 const unsigned* __restrict__ activev,
                                                 float* __restrict__ thr) {
    int b = blockIdx.x;
    if (!activev[b]) return;
    unsigned hi = hi_bin[b];
    if (hi == 0u) return;
    __shared__ unsigned rb, rr;
    select_bin(hist2 + (size_t)b * NBIN, rankv[b], &rb, &rr);
    if (threadIdx.x == 0) thr[b] = __uint_as_float((hi << 16) | rb);
}

// ---------------- K5: all dice sums (21 per sample) ---------------------------------
__global__ __launch_bounds__(256) void k_sums(const float* __restrict__ preds,
                                              const int* __restrict__ labels,
                                              const int* __restrict__ mask,
                                              const float* __restrict__ thr,
                                              float* __restrict__ sums) {
    int b = blockIdx.y;
    const float* pr = preds + (size_t)b * NCH * PX;
    const int* lb = labels + (size_t)b * NCH * PX;
    const int* mk = mask + (size_t)b * PX;
    float thr_b = thr[b];

    float a0 = 0.f, a1 = 0.f, a2 = 0.f;
    float sn[6] = {0.f, 0.f, 0.f, 0.f, 0.f, 0.f};
    float sp[6] = {0.f, 0.f, 0.f, 0.f, 0.f, 0.f};
    float sl[6] = {0.f, 0.f, 0.f, 0.f, 0.f, 0.f};

    for (int i = blockIdx.x * blockDim.x + threadIdx.x; i < PX; i += gridDim.x * blockDim.x) {
        float m  = (float)mk[i];
        float p6 = sigf(pr[6 * PX + i]);
        float pn = p6 * m;
        float Mi = (pn >= thr_b) ? 1.0f : 0.0f;
        float ln = (float)lb[6 * PX + i] * m;
        a0 += pn * ln * Mi;
        a1 += pn * pn * Mi;
        a2 += ln * Mi;
        float W = (pn >= 0.5f) ? 1.0f : 0.0f;
        #pragma unroll
        for (int c = 0; c < 6; c++) {
            float pc = sigf(pr[c * PX + i]);
            float lc = (float)lb[c * PX + i];
            sn[c] += pc * lc * W;
            sp[c] += pc * pc * W;
            sl[c] += lc * W;
        }
    }

    float vals[21];
    vals[0] = a0; vals[1] = a1; vals[2] = a2;
    #pragma unroll
    for (int c = 0; c < 6; c++) { vals[3 + c] = sn[c]; vals[9 + c] = sp[c]; vals[15 + c] = sl[c]; }

    __shared__ float red[4][21];
    int lane = threadIdx.x & 63, wid = threadIdx.x >> 6;
    #pragma unroll
    for (int j = 0; j < 21; j++) {
        float v = wred_f(vals[j]);
        if (lane == 0) red[wid][j] = v;
    }
    __syncthreads();
    if (threadIdx.x < 21) {
        float tot = red[0][threadIdx.x] + red[1][threadIdx.x] + red[2][threadIdx.x] + red[3][threadIdx.x];
        atomicAdd(&sums[b * 21 + threadIdx.x], tot);
    }
}

// ---------------- K6: final dice + means --------------------------------------------
__global__ void k_final(const float* __restrict__ sums, float* __restrict__ out) {
    int t = threadIdx.x;
    float Lc = 0.f, Ls = 0.f;
    if (t < BS) {
        const float* s = sums + t * 21;
        Lc = 1.0f - (2.0f * s[0]) / (s[1] + s[2] + EPSF);
        float acc = 0.f;
        #pragma unroll
        for (int c = 0; c < 6; c++)
            acc += (2.0f * s[3 + c]) / (s[9 + c] + s[15 + c] + EPSF);
        Ls = 1.0f - acc * (1.0f / 6.0f);
    }
    #pragma unroll
    for (int o = 4; o; o >>= 1) { Lc += __shfl_down(Lc, o); Ls += __shfl_down(Ls, o); }
    if (t == 0) {
        float lc_m = Lc * (1.0f / (float)BS);
        float ls_m = Ls * (1.0f / (float)BS);
        out[0] = lc_m;
        out[1] = ls_m;
        out[2] = 0.7f * lc_m + 0.3f * ls_m;
    }
}

extern "C" void kernel_launch(void* const* d_in, const int* in_sizes, int n_in,
                              void* d_out, int out_size, void* d_ws, size_t ws_size,
                              hipStream_t stream) {
    const float* preds = (const float*)d_in[0];
    const int* labels  = (const int*)d_in[1];
    const int* mask    = (const int*)d_in[2];
    float* out = (float*)d_out;

    // workspace layout (all u32/f32 slots)
    unsigned* hist1   = (unsigned*)d_ws;            // BS * NBIN
    unsigned* hist2   = hist1 + (size_t)BS * NBIN;  // BS * NBIN
    unsigned* n_pos   = hist2 + (size_t)BS * NBIN;  // BS
    unsigned* hi_bin  = n_pos + BS;                 // BS
    unsigned* rankv   = hi_bin + BS;                // BS
    unsigned* activev = rankv + BS;                 // BS
    float*    thr     = (float*)(activev + BS);     // BS
    float*    sums    = thr + BS;                   // BS * 21

    size_t zero_words = (size_t)2 * BS * NBIN + 5 * BS + (size_t)BS * 21;
    hipMemsetAsync(d_ws, 0, zero_words * sizeof(unsigned), stream);

    dim3 g1(80, BS);
    hipLaunchKernelGGL(k_hist, g1, dim3(256), 0, stream, preds, mask, hist1, n_pos);

    hipLaunchKernelGGL(k_find_hi, dim3(BS), dim3(256), 0, stream,
                       hist1, n_pos, hi_bin, rankv, activev, thr);

    dim3 g3(40, BS);
    hipLaunchKernelGGL(k_refine, g3, dim3(256), 0, stream,
                       preds, mask, hi_bin, activev, hist2);

    hipLaunchKernelGGL(k_find_lo, dim3(BS), dim3(256), 0, stream,
                       hist2, hi_bin, rankv, activev, thr);

    dim3 g5(160, BS);
    hipLaunchKernelGGL(k_sums, g5, dim3(256), 0, stream,
                       preds, labels, mask, thr, sums);

    hipLaunchKernelGGL(k_final, dim3(1), dim3(64), 0, stream, sums, out);
}

// Round 2
// 233.003 us; speedup vs baseline: 1.0753x; 1.0753x over previous
//
#include <hip/hip_runtime.h>

#define BS   8
#define NCH  7
#define PX   409600      // 640*640
#define NBIN 65536
#define NCHK 256
#define WIN_LO 0x3000u   // LDS histogram window over top-16 bits: [0x3000, 0x4000)
#define WIN_SZ 4096
#define EPSF 1e-6f

__device__ __forceinline__ float sigf(float x) {
    return 1.0f / (1.0f + __expf(-x));
}

__device__ __forceinline__ unsigned wred_u(unsigned v) {
    #pragma unroll
    for (int o = 32; o; o >>= 1) v += __shfl_down(v, o);
    return v;
}

__device__ __forceinline__ float wred_f(float v) {
    #pragma unroll
    for (int o = 32; o; o >>= 1) v += __shfl_down(v, o);
    return v;
}

// =====================================================================================
// K1: the single cold pass over ALL data.
//   - histogram (top-16-bit bins + 256 chunk sums) of negatives of pred_n, n_pos
//   - the 18 thr-independent L_s sums: sn[c], sp[c], sl[c] gated by W = (pred_n >= 0.5)
// =====================================================================================
__global__ __launch_bounds__(256) void k_main(const float* __restrict__ preds,
                                              const int* __restrict__ labels,
                                              const int* __restrict__ mask,
                                              unsigned* __restrict__ hist1,
                                              unsigned* __restrict__ chunks1,
                                              unsigned* __restrict__ n_pos,
                                              float* __restrict__ sums) {
    int b = blockIdx.y;
    const float* pr = preds + (size_t)b * NCH * PX;
    const int*   lb = labels + (size_t)b * NCH * PX;
    const int*   mk = mask + (size_t)b * PX;

    __shared__ unsigned lh[WIN_SZ];
    for (int j = threadIdx.x; j < WIN_SZ; j += 256) lh[j] = 0u;
    __syncthreads();

    unsigned pos_cnt = 0, zero_cnt = 0;
    float acc[18];
    #pragma unroll
    for (int j = 0; j < 18; j++) acc[j] = 0.f;

    for (int g = blockIdx.x * 256 + threadIdx.x; g < PX / 4; g += gridDim.x * 256) {
        int px = g * 4;
        float4 p6 = *(const float4*)(pr + 6 * PX + px);
        int4   m4 = *(const int4*)(mk + px);
        float mm[4]  = {(float)m4.x, (float)m4.y, (float)m4.z, (float)m4.w};
        float p6a[4] = {p6.x, p6.y, p6.z, p6.w};
        float W[4];
        #pragma unroll
        for (int u = 0; u < 4; u++) {
            float pn = sigf(p6a[u]) * mm[u];
            if (pn >= 0.5f) {
                pos_cnt++; W[u] = 1.0f;
            } else {
                W[u] = 0.0f;
                unsigned bits = __float_as_uint(pn);
                if (bits == 0u) {
                    zero_cnt++;
                } else {
                    unsigned hb = bits >> 16;
                    if (hb - WIN_LO < WIN_SZ) {
                        atomicAdd(&lh[hb - WIN_LO], 1u);
                    } else {   // rare fallback: keep bins + chunk sums consistent
                        atomicAdd(&hist1[(size_t)b * NBIN + hb], 1u);
                        atomicAdd(&chunks1[b * NCHK + (hb >> 8)], 1u);
                    }
                }
            }
        }
        #pragma unroll
        for (int c = 0; c < 6; c++) {
            float4 pc4 = *(const float4*)(pr + c * PX + px);
            int4   lc4 = *(const int4*)(lb + c * PX + px);
            float pcs[4] = {pc4.x, pc4.y, pc4.z, pc4.w};
            float lcs[4] = {(float)lc4.x, (float)lc4.y, (float)lc4.z, (float)lc4.w};
            #pragma unroll
            for (int u = 0; u < 4; u++) {
                float s = sigf(pcs[u]);
                float l = lcs[u];
                acc[c]      += s * l * W[u];   // sn[c]
                acc[6 + c]  += s * s * W[u];   // sp[c]
                acc[12 + c] += l * W[u];       // sl[c]
            }
        }
    }
    __syncthreads();

    // flush LDS window histogram to global bins (coalesced) ...
    for (int j = threadIdx.x; j < WIN_SZ; j += 256) {
        unsigned c = lh[j];
        if (c) atomicAdd(&hist1[(size_t)b * NBIN + WIN_LO + j], c);
    }
    // ... and produce the 16 window chunk sums (chunks 48..63)
    __shared__ unsigned csum[256];
    {
        unsigned s = 0;
        int chunk = threadIdx.x >> 4, part = threadIdx.x & 15;
        const unsigned* base = &lh[chunk * 256 + part * 16];
        #pragma unroll
        for (int j = 0; j < 16; j++) s += base[j];
        csum[threadIdx.x] = s;
    }
    __syncthreads();
    if (threadIdx.x < 16) {
        unsigned s = 0;
        #pragma unroll
        for (int j = 0; j < 16; j++) s += csum[threadIdx.x * 16 + j];
        if (s) atomicAdd(&chunks1[b * NCHK + 48 + threadIdx.x], s);
    }

    // block-reduce pos/zero counts
    __shared__ unsigned ws2[2][4];
    unsigned pv = wred_u(pos_cnt), zv = wred_u(zero_cnt);
    int lane = threadIdx.x & 63, wid = threadIdx.x >> 6;
    if (lane == 0) { ws2[0][wid] = pv; ws2[1][wid] = zv; }
    __syncthreads();
    if (threadIdx.x == 0) {
        unsigned pt = 0, zt = 0;
        #pragma unroll
        for (int w = 0; w < 4; w++) { pt += ws2[0][w]; zt += ws2[1][w]; }
        if (pt) atomicAdd(&n_pos[b], pt);
        if (zt) {
            atomicAdd(&hist1[(size_t)b * NBIN], zt);
            atomicAdd(&chunks1[b * NCHK], zt);
        }
    }

    // block-reduce the 18 L_s sums into sums[b][3..20]
    __shared__ float red[4][18];
    #pragma unroll
    for (int j = 0; j < 18; j++) {
        float v = wred_f(acc[j]);
        if (lane == 0) red[wid][j] = v;
    }
    __syncthreads();
    if (threadIdx.x < 18) {
        float tot = red[0][threadIdx.x] + red[1][threadIdx.x] +
                    red[2][threadIdx.x] + red[3][threadIdx.x];
        atomicAdd(&sums[b * 21 + 3 + threadIdx.x], tot);
    }
}

// =====================================================================================
// two-level coalesced select: chunks[256] (chunk c = bins [c*256,(c+1)*256)), bins[65536]
// finds bin s.t. count(elements in bins >= bin) >= k, strictly < k above; rank in bin.
// =====================================================================================
__device__ void select2(const unsigned* __restrict__ chunks,
                        const unsigned* __restrict__ bins,
                        unsigned k, unsigned* out_bin, unsigned* out_rank) {
    __shared__ unsigned cs[256];
    __shared__ unsigned sel_c, sel_r;
    int t = threadIdx.x;
    cs[t] = chunks[t];                 // coalesced
    __syncthreads();
    #pragma unroll
    for (int off = 1; off < 256; off <<= 1) {
        unsigned v = cs[t];
        unsigned a = (t + off < 256) ? cs[t + off] : 0u;
        __syncthreads();
        cs[t] = v + a;
        __syncthreads();
    }
    {
        unsigned sfx  = cs[t];
        unsigned sfx1 = (t < 255) ? cs[t + 1] : 0u;
        if (sfx >= k && sfx1 < k) { sel_c = (unsigned)t; sel_r = k - sfx1; }
    }
    __syncthreads();
    unsigned chunk = sel_c, krem = sel_r;
    cs[t] = bins[chunk * 256 + t];     // coalesced
    __syncthreads();
    #pragma unroll
    for (int off = 1; off < 256; off <<= 1) {
        unsigned v = cs[t];
        unsigned a = (t + off < 256) ? cs[t + off] : 0u;
        __syncthreads();
        cs[t] = v + a;
        __syncthreads();
    }
    {
        unsigned sfx  = cs[t];
        unsigned sfx1 = (t < 255) ? cs[t + 1] : 0u;
        if (sfx >= krem && sfx1 < krem) {
            *out_bin  = chunk * 256 + (unsigned)t;
            *out_rank = krem - sfx1;
        }
    }
    __syncthreads();
}

// ---------------- K2: find top-16-bit bin of the k-th largest negative --------------
__global__ __launch_bounds__(256) void k_find_hi(const unsigned* __restrict__ hist1,
                                                 const unsigned* __restrict__ chunks1,
                                                 const unsigned* __restrict__ n_pos,
                                                 unsigned* __restrict__ hi_bin,
                                                 unsigned* __restrict__ rankv,
                                                 unsigned* __restrict__ activev,
                                                 float* __restrict__ thr) {
    int b = blockIdx.x;
    unsigned np_ = n_pos[b];
    unsigned k = np_ * 3u;
    unsigned nneg = (unsigned)PX - np_;
    if (!(nneg > k && k > 0u)) {
        if (threadIdx.x == 0) { activev[b] = 0u; thr[b] = -1.0f; }  // M = 1 everywhere
        return;
    }
    __shared__ unsigned rb, rr;
    select2(chunks1 + b * NCHK, hist1 + (size_t)b * NBIN, k, &rb, &rr);
    if (threadIdx.x == 0) {
        activev[b] = 1u;
        hi_bin[b] = rb;
        rankv[b] = rr;
        // bin 0: pixels with pn==0 contribute 0 to every L_c sum under any M,
        // so thr=0.0f (include all of them) is exactly equivalent.
        if (rb == 0u) thr[b] = 0.0f;
    }
}

// ---------------- K3: refine — low-16-bit histogram within selected hi bin ----------
__global__ __launch_bounds__(256) void k_refine(const float* __restrict__ preds,
                                                const int* __restrict__ mask,
                                                const unsigned* __restrict__ hi_bin,
                                                const unsigned* __restrict__ activev,
                                                unsigned* __restrict__ hist2,
                                                unsigned* __restrict__ chunks2) {
    int b = blockIdx.y;
    if (!activev[b]) return;
    unsigned hi = hi_bin[b];
    if (hi == 0u) return;   // thr already resolved to 0.0f
    const float* pr = preds + ((size_t)b * NCH + 6) * PX;
    const int* mk = mask + (size_t)b * PX;
    unsigned* h2 = hist2 + (size_t)b * NBIN;
    unsigned* c2 = chunks2 + b * NCHK;
    for (int g = blockIdx.x * 256 + threadIdx.x; g < PX / 4; g += gridDim.x * 256) {
        int px = g * 4;
        float4 p6 = *(const float4*)(pr + px);
        int4   m4 = *(const int4*)(mk + px);
        float p6a[4] = {p6.x, p6.y, p6.z, p6.w};
        float mm[4]  = {(float)m4.x, (float)m4.y, (float)m4.z, (float)m4.w};
        #pragma unroll
        for (int u = 0; u < 4; u++) {
            float pn = sigf(p6a[u]) * mm[u];
            if (pn < 0.5f) {
                unsigned bits = __float_as_uint(pn);
                if ((bits >> 16) == hi) {
                    unsigned lo = bits & 0xFFFFu;
                    atomicAdd(&h2[lo], 1u);
                    atomicAdd(&c2[lo >> 8], 1u);
                }
            }
        }
    }
}

// ---------------- K4: resolve exact threshold bits ----------------------------------
__global__ __launch_bounds__(256) void k_find_lo(const unsigned* __restrict__ hist2,
                                                 const unsigned* __restrict__ chunks2,
                                                 const unsigned* __restrict__ hi_bin,
                                                 const unsigned* __restrict__ rankv,
                                                 const unsigned* __restrict__ activev,
                                                 float* __restrict__ thr) {
    int b = blockIdx.x;
    if (!activev[b]) return;
    unsigned hi = hi_bin[b];
    if (hi == 0u) return;
    __shared__ unsigned rb, rr;
    select2(chunks2 + b * NCHK, hist2 + (size_t)b * NBIN, rankv[b], &rb, &rr);
    if (threadIdx.x == 0) thr[b] = __uint_as_float((hi << 16) | rb);
}

// ---------------- K5: the 3 thr-dependent L_c sums (ch6 + mask only, L3-hot) --------
__global__ __launch_bounds__(256) void k_lc(const float* __restrict__ preds,
                                            const int* __restrict__ labels,
                                            const int* __restrict__ mask,
                                            const float* __restrict__ thr,
                                            float* __restrict__ sums) {
    int b = blockIdx.y;
    const float* pr = preds + ((size_t)b * NCH + 6) * PX;
    const int*   lb = labels + ((size_t)b * NCH + 6) * PX;
    const int*   mk = mask + (size_t)b * PX;
    float thr_b = thr[b];

    float a0 = 0.f, a1 = 0.f, a2 = 0.f;
    for (int g = blockIdx.x * 256 + threadIdx.x; g < PX / 4; g += gridDim.x * 256) {
        int px = g * 4;
        float4 p6 = *(const float4*)(pr + px);
        int4   l4 = *(const int4*)(lb + px);
        int4   m4 = *(const int4*)(mk + px);
        float p6a[4] = {p6.x, p6.y, p6.z, p6.w};
        float la[4]  = {(float)l4.x, (float)l4.y, (float)l4.z, (float)l4.w};
        float mm[4]  = {(float)m4.x, (float)m4.y, (float)m4.z, (float)m4.w};
        #pragma unroll
        for (int u = 0; u < 4; u++) {
            float pn = sigf(p6a[u]) * mm[u];
            float Mi = (pn >= thr_b) ? 1.0f : 0.0f;
            float ln = la[u] * mm[u];
            a0 += pn * ln * Mi;
            a1 += pn * pn * Mi;
            a2 += ln * Mi;
        }
    }
    __shared__ float red[4][3];
    int lane = threadIdx.x & 63, wid = threadIdx.x >> 6;
    float v0 = wred_f(a0), v1 = wred_f(a1), v2 = wred_f(a2);
    if (lane == 0) { red[wid][0] = v0; red[wid][1] = v1; red[wid][2] = v2; }
    __syncthreads();
    if (threadIdx.x < 3) {
        float tot = red[0][threadIdx.x] + red[1][threadIdx.x] +
                    red[2][threadIdx.x] + red[3][threadIdx.x];
        atomicAdd(&sums[b * 21 + threadIdx.x], tot);
    }
}

// ---------------- K6: final dice + means --------------------------------------------
__global__ void k_final(const float* __restrict__ sums, float* __restrict__ out) {
    int t = threadIdx.x;
    float Lc = 0.f, Ls = 0.f;
    if (t < BS) {
        const float* s = sums + t * 21;
        Lc = 1.0f - (2.0f * s[0]) / (s[1] + s[2] + EPSF);
        float acc = 0.f;
        #pragma unroll
        for (int c = 0; c < 6; c++)
            acc += (2.0f * s[3 + c]) / (s[9 + c] + s[15 + c] + EPSF);
        Ls = 1.0f - acc * (1.0f / 6.0f);
    }
    #pragma unroll
    for (int o = 4; o; o >>= 1) { Lc += __shfl_down(Lc, o); Ls += __shfl_down(Ls, o); }
    if (t == 0) {
        float lc_m = Lc * (1.0f / (float)BS);
        float ls_m = Ls * (1.0f / (float)BS);
        out[0] = lc_m;
        out[1] = ls_m;
        out[2] = 0.7f * lc_m + 0.3f * ls_m;
    }
}

extern "C" void kernel_launch(void* const* d_in, const int* in_sizes, int n_in,
                              void* d_out, int out_size, void* d_ws, size_t ws_size,
                              hipStream_t stream) {
    const float* preds = (const float*)d_in[0];
    const int* labels  = (const int*)d_in[1];
    const int* mask    = (const int*)d_in[2];
    float* out = (float*)d_out;

    // workspace layout (u32/f32 words)
    unsigned* hist1   = (unsigned*)d_ws;              // BS * NBIN
    unsigned* hist2   = hist1 + (size_t)BS * NBIN;    // BS * NBIN
    unsigned* chunks1 = hist2 + (size_t)BS * NBIN;    // BS * NCHK
    unsigned* chunks2 = chunks1 + (size_t)BS * NCHK;  // BS * NCHK
    unsigned* n_pos   = chunks2 + (size_t)BS * NCHK;  // BS
    unsigned* hi_bin  = n_pos + BS;                   // BS
    unsigned* rankv   = hi_bin + BS;                  // BS
    unsigned* activev = rankv + BS;                   // BS
    float*    thr     = (float*)(activev + BS);       // BS
    float*    sums    = thr + BS;                     // BS * 21

    size_t zero_words = (size_t)2 * BS * NBIN + (size_t)2 * BS * NCHK + 5 * BS + (size_t)BS * 21;
    hipMemsetAsync(d_ws, 0, zero_words * sizeof(unsigned), stream);

    // K1: PX/4 = 102400 groups; 100*256 threads -> exactly 4 groups each
    hipLaunchKernelGGL(k_main, dim3(100, BS), dim3(256), 0, stream,
                       preds, labels, mask, hist1, chunks1, n_pos, sums);

    hipLaunchKernelGGL(k_find_hi, dim3(BS), dim3(256), 0, stream,
                       hist1, chunks1, n_pos, hi_bin, rankv, activev, thr);

    hipLaunchKernelGGL(k_refine, dim3(32, BS), dim3(256), 0, stream,
                       preds, mask, hi_bin, activev, hist2, chunks2);

    hipLaunchKernelGGL(k_find_lo, dim3(BS), dim3(256), 0, stream,
                       hist2, chunks2, hi_bin, rankv, activev, thr);

    hipLaunchKernelGGL(k_lc, dim3(100, BS), dim3(256), 0, stream,
                       preds, labels, mask, thr, sums);

    hipLaunchKernelGGL(k_final, dim3(1), dim3(64), 0, stream, sums, out);
}